// Round 1
// baseline (2975.682 us; speedup 1.0000x reference)
//
#include <hip/hip_runtime.h>
#include <math.h>

typedef unsigned int u32;
typedef unsigned long long u64;

#define BATCH 64
#define A_TOT 8649
#define TOPN  6000
#define POST  1500
#define NB    4096
#define NT    1024
#define KEY_STRIDE 8704
#define NOACT 0x1FFFu
#define NSLOT 6

// One block per batch image. Phases:
//  1) stable descending sort of (score, index) via LDS counting sort + per-bucket
//     insertion sort on 64-bit keys (key = score_bits<<32 | ~idx  -> exact lax.top_k
//     tie semantics: equal scores ordered by ascending original index)
//  2) decode top-6000 boxes into per-thread registers (6 candidates/thread),
//     exp computed in double -> correctly-rounded fp32 (matches a careful fp32 ref)
//  3) sequential greedy NMS: since scores are sorted descending, argmax == first
//     active index. 2 barriers/pick, no global memory ops inside the pick loop.
__global__ __launch_bounds__(NT, 4) void roibbox_kernel(
    const float* __restrict__ deltas,    // [B, A, 4] (viewed from [B,31,31,36])
    const float* __restrict__ probs,     // [B, A]
    const float* __restrict__ anchors,   // [A, 4]
    float* __restrict__ out,             // [B*POST*4] boxes then [B*POST] scores
    u64* __restrict__ wskeys)            // [B, KEY_STRIDE]
{
    #pragma clang fp contract(off)
    __shared__ u32 bucketA[NB];      // counts -> bucket starts
    __shared__ u32 bucketB[NB];      // scatter cursors -> bucket ends
    __shared__ u32 stemp[2*NT];      // scan ping-pong
    __shared__ float selS[8];        // selected box broadcast: y1,x1,y2,x2,area
    __shared__ u32 slot;             // epoch-encoded argmin slot

    const int tid = threadIdx.x;
    const int b   = blockIdx.x;
    const float* pb = probs + (size_t)b * A_TOT;
    u64* keys = wskeys + (size_t)b * KEY_STRIDE;

    // ---------- init ----------
    #pragma unroll
    for (int i = 0; i < NB/NT; ++i) bucketA[tid + i*NT] = 0u;
    if (tid == 0) slot = 0xFFFFFFFFu;
    __syncthreads();

    // ---------- histogram (bucket by score; reversed so bucket 0 = highest) ----------
    for (int j = tid; j < A_TOT; j += NT) {
        float s = pb[j];
        int bkt = (int)(s * (float)NB);
        bkt = (NB-1) - min(max(bkt, 0), NB-1);
        atomicAdd(&bucketA[bkt], 1u);
    }
    __syncthreads();

    // ---------- exclusive scan over 4096 counts (4 per thread + Hillis-Steele) ----------
    {
        int base = tid << 2;
        u32 c0 = bucketA[base+0], c1 = bucketA[base+1], c2 = bucketA[base+2], c3 = bucketA[base+3];
        u32 mysum = c0 + c1 + c2 + c3;
        stemp[tid] = mysum;
        __syncthreads();
        int src = 0;
        for (int off = 1; off < NT; off <<= 1) {
            u32 v = stemp[src*NT + tid];
            if (tid >= off) v += stemp[src*NT + tid - off];
            stemp[(src^1)*NT + tid] = v;
            __syncthreads();
            src ^= 1;
        }
        u32 excl = stemp[src*NT + tid] - mysum;
        u32 e0 = excl, e1 = e0 + c0, e2 = e1 + c1, e3 = e2 + c2;
        bucketA[base+0] = e0; bucketB[base+0] = e0;
        bucketA[base+1] = e1; bucketB[base+1] = e1;
        bucketA[base+2] = e2; bucketB[base+2] = e2;
        bucketA[base+3] = e3; bucketB[base+3] = e3;
    }
    __syncthreads();

    // ---------- scatter keys to workspace ----------
    for (int j = tid; j < A_TOT; j += NT) {
        float s = pb[j];
        int bkt = (int)(s * (float)NB);
        bkt = (NB-1) - min(max(bkt, 0), NB-1);
        u32 pos = atomicAdd(&bucketB[bkt], 1u);
        keys[pos] = ((u64)__float_as_uint(s) << 32) | (u64)(~(u32)j);
    }
    __syncthreads();

    // ---------- per-bucket insertion sort (descending; keys unique) ----------
    for (int bkt = tid; bkt < NB; bkt += NT) {
        int begin = (int)bucketA[bkt], end = (int)bucketB[bkt];
        for (int k = begin + 1; k < end; ++k) {
            u64 key = keys[k];
            int m = k - 1;
            while (m >= begin && keys[m] < key) { keys[m+1] = keys[m]; --m; }
            keys[m+1] = key;
        }
    }
    __syncthreads();

    // ---------- decode my 6 candidates into registers ----------
    float ry1[NSLOT], rx1[NSLOT], ry2[NSLOT], rx2[NSLOT], rA[NSLOT], rS[NSLOT];
    u32 mask = 0;
    #pragma unroll
    for (int i = 0; i < NSLOT; ++i) {
        ry1[i]=0.f; rx1[i]=0.f; ry2[i]=0.f; rx2[i]=0.f; rA[i]=0.f; rS[i]=0.f;
        int j = tid + i*NT;
        if (j < TOPN) {
            u64 k = keys[j];
            u32 aidx = ~((u32)k);
            rS[i] = __uint_as_float((u32)(k >> 32));
            float4 av = *(const float4*)(anchors + (size_t)aidx*4);
            float4 dv = *(const float4*)(deltas + ((size_t)b*A_TOT + aidx)*4);
            float d0 = dv.x*0.1f, d1 = dv.y*0.1f, d2 = dv.z*0.2f, d3 = dv.w*0.2f;
            float ah = av.z - av.x, aw = av.w - av.y;
            float acy = av.x + 0.5f*ah, acx = av.y + 0.5f*aw;
            float h = (float)exp((double)d2) * ah;   // correctly-rounded fp32 exp
            float w = (float)exp((double)d3) * aw;
            float cy = d0*ah + acy;                  // contract(off): mul then add
            float cx = d1*aw + acx;
            ry1[i] = cy - 0.5f*h; rx1[i] = cx - 0.5f*w;
            ry2[i] = cy + 0.5f*h; rx2[i] = cx + 0.5f*w;
            rA[i] = (ry2[i]-ry1[i])*(rx2[i]-rx1[i]);
            mask |= 1u << i;
        }
    }
    u32 pp0=0xFFFFFFFFu, pp1=0xFFFFFFFFu, pp2=0xFFFFFFFFu,
        pp3=0xFFFFFFFFu, pp4=0xFFFFFFFFu, pp5=0xFFFFFFFFu;
    __syncthreads();

    // ---------- greedy NMS: pick = first active (scores sorted desc) ----------
    u32 cur = 0;   // position 0 always the first pick
    int pend = POST;
    for (int p = 0; p < POST; ++p) {
        if (tid == (int)(cur & (u32)(NT-1))) {
            u32 ii = cur >> 10;
            float v0=ry1[0], v1=rx1[0], v2=ry2[0], v3=rx2[0], v4=rA[0];
            if (ii==1){v0=ry1[1];v1=rx1[1];v2=ry2[1];v3=rx2[1];v4=rA[1];}
            else if (ii==2){v0=ry1[2];v1=rx1[2];v2=ry2[2];v3=rx2[2];v4=rA[2];}
            else if (ii==3){v0=ry1[3];v1=rx1[3];v2=ry2[3];v3=rx2[3];v4=rA[3];}
            else if (ii==4){v0=ry1[4];v1=rx1[4];v2=ry2[4];v3=rx2[4];v4=rA[4];}
            else if (ii==5){v0=ry1[5];v1=rx1[5];v2=ry2[5];v3=rx2[5];v4=rA[5];}
            selS[0]=v0; selS[1]=v1; selS[2]=v2; selS[3]=v3; selS[4]=v4;
            if (ii==0) pp0=(u32)p; else if (ii==1) pp1=(u32)p; else if (ii==2) pp2=(u32)p;
            else if (ii==3) pp3=(u32)p; else if (ii==4) pp4=(u32)p; else pp5=(u32)p;
        }
        __syncthreads();   // barrier A: sel visible (LDS only -> cheap drain)
        float sy1=selS[0], sx1=selS[1], sy2=selS[2], sx2=selS[3], sA=selS[4];
        // area quick-reject: iou <= min(A)/max(A); margins provably can't flip
        // any reference decision (0.699*(1+eps) << 0.7f)
        float loA = 0.699f * sA;
        float hiA = 1.4307f * sA;
        #pragma unroll
        for (int i = 0; i < NSLOT; ++i) {
            if (mask & (1u << i)) {
                float bA = rA[i];
                if (bA >= loA && bA <= hiA) {
                    float yy1 = fmaxf(sy1, ry1[i]);
                    float xx1 = fmaxf(sx1, rx1[i]);
                    float yy2 = fminf(sy2, ry2[i]);
                    float xx2 = fminf(sx2, rx2[i]);
                    float iy = fmaxf(yy2 - yy1, 0.0f);
                    float ix = fmaxf(xx2 - xx1, 0.0f);
                    float inter = iy * ix;
                    float den = ((sA + bA) - inter) + 1e-9f;  // exact ref order
                    if (inter / den > 0.7f) mask &= ~(1u << i);
                }
            }
        }
        u32 lmin = mask ? ((u32)tid | ((u32)__builtin_ctz(mask) << 10)) : NOACT;
        #pragma unroll
        for (int off = 32; off; off >>= 1)
            lmin = min(lmin, (u32)__shfl_xor((int)lmin, off, 64));
        u32 epoch = (u32)(POST - p);   // decreasing -> stale entries always larger
        if ((tid & 63) == 0 && lmin != NOACT)
            atomicMin(&slot, (epoch << 13) | lmin);
        __syncthreads();   // barrier B: argmin final
        u32 v = slot;
        if ((v >> 13) != epoch) { pend = p + 1; break; }  // no survivors
        cur = v & 8191u;
    }

    // ---------- epilogue: deferred output writes ----------
    const size_t sbase = (size_t)BATCH * POST * 4;
    #pragma unroll
    for (int i = 0; i < NSLOT; ++i) {
        u32 ppv = (i==0)?pp0:(i==1)?pp1:(i==2)?pp2:(i==3)?pp3:(i==4)?pp4:pp5;
        if (ppv != 0xFFFFFFFFu) {
            size_t row = (size_t)b * POST + ppv;
            float* ob = out + row * 4;
            ob[0] = fminf(fmaxf(ry1[i], 0.f), 1.f);
            ob[1] = fminf(fmaxf(rx1[i], 0.f), 1.f);
            ob[2] = fminf(fmaxf(ry2[i], 0.f), 1.f);
            ob[3] = fminf(fmaxf(rx2[i], 0.f), 1.f);
            out[sbase + row] = rS[i];
        }
    }
    for (int p = pend + tid; p < POST; p += NT) {
        size_t row = (size_t)b * POST + p;
        float* ob = out + row * 4;
        ob[0]=0.f; ob[1]=0.f; ob[2]=0.f; ob[3]=0.f;
        out[sbase + row] = 0.f;
    }
}

extern "C" void kernel_launch(void* const* d_in, const int* in_sizes, int n_in,
                              void* d_out, int out_size, void* d_ws, size_t ws_size,
                              hipStream_t stream) {
    const float* deltas  = (const float*)d_in[0];  // [64,31,31,36] f32
    const float* probs   = (const float*)d_in[1];  // [64,31,31,9]  f32
    // d_in[2] = gt_labels (unused)
    const float* anchors = (const float*)d_in[3];  // [8649,4] f32
    float* out = (float*)d_out;                    // 480000 f32
    u64* wskeys = (u64*)d_ws;                      // 64*8704*8 = 4.46 MB

    roibbox_kernel<<<dim3(BATCH), dim3(NT), 0, stream>>>(deltas, probs, anchors, out, wskeys);
}